// Round 10
// baseline (73.101 us; speedup 1.0000x reference)
//
#include <hip/hip_runtime.h>
#include <hip/hip_bf16.h>
#include <stdint.h>

typedef __bf16 bf16x8 __attribute__((ext_vector_type(8)));
typedef __bf16 bf16x4 __attribute__((ext_vector_type(4)));
typedef float  f32x4  __attribute__((ext_vector_type(4)));

#define NROWS 16384
#define NFEAT 26
#define VOCAB 100000

// lgkm-only barrier: syncs LDS but leaves global (vmcnt) prefetches in flight.
__device__ __forceinline__ void bar_lgkm() {
  asm volatile("s_waitcnt lgkmcnt(0)" ::: "memory");
  __builtin_amdgcn_s_barrier();
  asm volatile("" ::: "memory");
}

// ---------------- per-layer GEMM (layers 2-4): A (LDS) x W[KREAL][N] fp32 ----------
template<int KPAD, int KREAL, int N, int NCT, int WS>
__device__ __forceinline__ void mlp_layer(const float* __restrict__ W,
                                          const float* __restrict__ bias,
                                          const __bf16* Ain, __bf16* Aout,
                                          int w, int lane) {
  constexpr int LDA = KPAD + 8, LDO = N + 8;
  const int lrow = lane & 15;
  const int kg = (lane >> 4) * 8;

  f32x4 acc[NCT][4];
  #pragma unroll
  for (int j = 0; j < NCT; ++j)
    #pragma unroll
    for (int m = 0; m < 4; ++m)
      #pragma unroll
      for (int i = 0; i < 4; ++i) acc[j][m][i] = 0.f;

  int col[NCT];
  #pragma unroll
  for (int j = 0; j < NCT; ++j) col[j] = (w + j * WS) * 16 + lrow;

  for (int k0 = 0; k0 < KREAL; k0 += 32) {
    bf16x8 af[4];
    #pragma unroll
    for (int m = 0; m < 4; ++m)
      af[m] = *(const bf16x8*)(Ain + (m * 16 + lrow) * LDA + k0 + kg);
    #pragma unroll
    for (int j = 0; j < NCT; ++j) {
      bf16x8 bw;
      #pragma unroll
      for (int i = 0; i < 8; ++i)
        bw[i] = (__bf16)W[(size_t)(k0 + kg + i) * N + col[j]];
      #pragma unroll
      for (int m = 0; m < 4; ++m)
        acc[j][m] = __builtin_amdgcn_mfma_f32_16x16x32_bf16(af[m], bw, acc[j][m], 0, 0, 0);
    }
  }

  const int rbase = (lane >> 4) * 4;
  #pragma unroll
  for (int j = 0; j < NCT; ++j) {
    float bv = bias[col[j]];
    #pragma unroll
    for (int m = 0; m < 4; ++m)
      #pragma unroll
      for (int i = 0; i < 4; ++i) {
        float v = acc[j][m][i] + bv;
        v = fmaxf(v, 0.f);
        Aout[(m * 16 + rbase + i) * LDO + col[j]] = (__bf16)v;
      }
  }
}

// Producer helpers: chunk c covers features 4c..4c+3 (K-cols c*64..c*64+63).
// Lane mapping (512 producer lanes): pr=row(0..63), a=feat-pair, q=dim-quad.
#define P_ISSUE(c)                                                            \
  if ((c) < 6 || a == 0) {                                                    \
    int f_ = 4 * (c) + 2 * a;                                                 \
    int i0_ = s_idx[sbase + f_], i1_ = s_idx[sbase + f_ + 1];                 \
    pe[(c)][0] = *(const f32x4*)(emb + ((size_t)f_ * VOCAB + i0_) * 16 + q4); \
    pe[(c)][1] = *(const f32x4*)(emb + ((size_t)(f_ + 1) * VOCAB + i1_) * 16 + q4); \
  }

#define P_CONSUME(c)                                                          \
  if ((c) < 6 || a == 0) {                                                    \
    int f_ = 4 * (c) + 2 * a;                                                 \
    bf16x4 pk0, pk1;                                                          \
    for (int i = 0; i < 4; ++i) {                                             \
      float v0 = pe[(c)][0][i], v1 = pe[(c)][1][i];                           \
      fsum[i] += v0 + v1; fsq[i] += v0 * v0 + v1 * v1;                        \
      pk0[i] = (__bf16)v0; pk1[i] = (__bf16)v1;                               \
    }                                                                         \
    *(bf16x4*)(A0 + pr * 456 + f_ * 16 + q4) = pk0;                           \
    *(bf16x4*)(A0 + pr * 456 + (f_ + 1) * 16 + q4) = pk1;                     \
  } else {                                                                    \
    bf16x4 pk, pz;                                                            \
    for (int i = 0; i < 4; ++i) { pk[i] = (__bf16)txv[i]; pz[i] = (__bf16)0.f; } \
    *(bf16x4*)(A0 + pr * 456 + 416 + q4) = pk;                                \
    *(bf16x4*)(A0 + pr * 456 + 432 + q4) = pz;                                \
  }

// ---------------- fused: producer/consumer wave-specialized layer-1 + tail ---------
__global__ __launch_bounds__(1024) void k_fused(
    const float* __restrict__ x_int,   // [B,13]
    const int*   __restrict__ x_cat,   // [B,26]
    const float* __restrict__ emb,     // [26,V,16]
    const float* __restrict__ lin,     // [26,V]
    const float* __restrict__ W_num,   // [13]
    const float* __restrict__ b_num,   // [1]
    const float* __restrict__ bias0,   // [1]
    const float* __restrict__ W1, const float* __restrict__ b1,
    const float* __restrict__ W2, const float* __restrict__ b2,
    const float* __restrict__ W3, const float* __restrict__ b3,
    const float* __restrict__ W4, const float* __restrict__ b4,
    const float* __restrict__ W5, const float* __restrict__ b5,
    float* __restrict__ out) {
  // LDS (125184 B): A0 @0 : 64x456 bf16; A1 @58368 : 64x520 bf16 (s_idx aliases
  // A1 head; last s_idx read is before producer barrier 5 < consumer A1 write).
  __shared__ __align__(16) char smem[125184];
  __bf16* A0 = (__bf16*)smem;
  __bf16* A1 = (__bf16*)(smem + 58368);
  int* s_idx = (int*)(smem + 58368);
  float* s_part = (float*)(smem + 124928);

  const int t = threadIdx.x;
  const int row0 = blockIdx.x * 64;
  const int w = t >> 6, lane = t & 63;
  const int lrow = lane & 15, kg = (lane >> 4) * 8;

  // ---- stage categorical indices (all waves) ----
  for (int i = t; i < 64 * NFEAT; i += 1024) {
    int r = i / NFEAT, f = i - r * NFEAT;
    s_idx[i] = x_cat[(size_t)(row0 + r) * NFEAT + f];
  }
  __syncthreads();                                   // B0

  if (w < 8) {
    // ================= PRODUCER waves (scattered streams only) =================
    const int pid = t;                 // 0..511
    const int pr = pid >> 3;           // row 0..63
    const int sub = pid & 7, a = sub >> 2, q4 = (sub & 3) * 4;
    const int sbase = pr * NFEAT;

    // lin gather: feats {sub, sub+8, sub+16, sub+24(if sub<2)}
    float lin_acc = lin[(size_t)sub * VOCAB + s_idx[sbase + sub]]
                  + lin[(size_t)(sub + 8) * VOCAB + s_idx[sbase + sub + 8]]
                  + lin[(size_t)(sub + 16) * VOCAB + s_idx[sbase + sub + 16]];
    if (sub < 2)
      lin_acc += lin[(size_t)(sub + 24) * VOCAB + s_idx[sbase + sub + 24]];
    // lin_num: ints {sub, sub+8(if sub<5)}
    float lnum = x_int[(size_t)(row0 + pr) * 13 + sub] * W_num[sub];
    if (sub < 5)
      lnum += x_int[(size_t)(row0 + pr) * 13 + sub + 8] * W_num[sub + 8];
    // x_int tail (chunk 6, a==1 lanes): cols 416..431
    float txv[4] = {0.f, 0.f, 0.f, 0.f};
    if (a == 1) {
      #pragma unroll
      for (int i = 0; i < 4; ++i) {
        int ii = q4 + i;
        if (ii < 13) txv[i] = x_int[(size_t)(row0 + pr) * 13 + ii];
      }
    }

    float fsum[4] = {0.f,0.f,0.f,0.f}, fsq[4] = {0.f,0.f,0.f,0.f};
    f32x4 pe[7][2];
    P_ISSUE(0); P_ISSUE(1);
    P_ISSUE(2); P_CONSUME(0); bar_lgkm();            // B1
    P_ISSUE(3); P_CONSUME(1); bar_lgkm();            // B2
    P_ISSUE(4); P_CONSUME(2); bar_lgkm();            // B3
    P_ISSUE(5); P_CONSUME(3); bar_lgkm();            // B4
    P_ISSUE(6); P_CONSUME(4); bar_lgkm();            // B5
    P_CONSUME(5); bar_lgkm();                        // B6
    P_CONSUME(6); bar_lgkm();                        // B7

    // FM + linear reduce (8-lane row group: xor4 over a, xor1/2 over q)
    #pragma unroll
    for (int i = 0; i < 4; ++i) {
      fsum[i] += __shfl_xor(fsum[i], 4);
      fsq[i]  += __shfl_xor(fsq[i], 4);
    }
    float fmq = 0.f;
    #pragma unroll
    for (int i = 0; i < 4; ++i) fmq += fsum[i] * fsum[i] - fsq[i];
    fmq += __shfl_xor(fmq, 1);
    fmq += __shfl_xor(fmq, 2);
    float lt = lin_acc + lnum;
    lt += __shfl_xor(lt, 1); lt += __shfl_xor(lt, 2); lt += __shfl_xor(lt, 4);
    if (sub == 0) s_part[pr] = 0.5f * fmq + lt + bias0[0] + b_num[0];
  } else {
    // ================= CONSUMER waves (W1 stream + layer-1 MFMA) =================
    const int cw = w - 8;
    f32x4 acc[4][4];
    #pragma unroll
    for (int j = 0; j < 4; ++j)
      #pragma unroll
      for (int m = 0; m < 4; ++m)
        #pragma unroll
        for (int i = 0; i < 4; ++i) acc[j][m][i] = 0.f;
    int col[4];
    #pragma unroll
    for (int j = 0; j < 4; ++j) col[j] = (cw + j * 8) * 16 + lrow;

    #pragma unroll
    for (int c = 0; c < 7; ++c) {
      bar_lgkm();                                    // B1..B7
      #pragma unroll
      for (int ks = 0; ks < 2; ++ks) {
        const int k0 = c * 64 + ks * 32;
        bf16x8 af[4];
        #pragma unroll
        for (int m = 0; m < 4; ++m)
          af[m] = *(const bf16x8*)(A0 + (m * 16 + lrow) * 456 + k0 + kg);
        #pragma unroll
        for (int j = 0; j < 4; ++j) {
          bf16x8 bw;
          #pragma unroll
          for (int i = 0; i < 8; ++i) {
            int k = k0 + kg + i;
            float v;
            if (c < 6) v = W1[(size_t)k * 512 + col[j]];
            else       v = (k < 429) ? W1[(size_t)k * 512 + col[j]] : 0.f;
            bw[i] = (__bf16)v;
          }
          #pragma unroll
          for (int m = 0; m < 4; ++m)
            acc[j][m] = __builtin_amdgcn_mfma_f32_16x16x32_bf16(af[m], bw, acc[j][m], 0, 0, 0);
        }
      }
    }
    // layer-1 epilogue: bias + ReLU -> A1 (s_idx alias dead: last read < B5)
    const int rbase = (lane >> 4) * 4;
    #pragma unroll
    for (int j = 0; j < 4; ++j) {
      float bv = b1[col[j]];
      #pragma unroll
      for (int m = 0; m < 4; ++m)
        #pragma unroll
        for (int i = 0; i < 4; ++i) {
          float v = acc[j][m][i] + bv;
          v = fmaxf(v, 0.f);
          A1[(m * 16 + rbase + i) * 520 + col[j]] = (__bf16)v;
        }
    }
  }
  __syncthreads();                                   // B8

  // ---- layers 2-4 (fp32 weights direct from read-only inputs, all waves) ----
  mlp_layer<512, 512, 256, 1, 16>(W2, b2, A1, A0, w, lane);
  __syncthreads();                                   // B9
  if (w < 8) mlp_layer<256, 256, 128, 1, 8>(W3, b3, A0, A1, w, lane);
  __syncthreads();                                   // B10
  if (w < 4) mlp_layer<128, 128, 64, 1, 4>(W4, b4, A1, A0, w, lane);
  __syncthreads();                                   // B11

  // ---- final 64->1 dot + combine ----
  {
    const int rr = t >> 4, gg = t & 15;
    float s = 0.f;
    #pragma unroll
    for (int i = 0; i < 4; ++i)
      s += (float)A0[rr * 72 + gg * 4 + i] * W5[gg * 4 + i];
    #pragma unroll
    for (int off = 1; off < 16; off <<= 1) s += __shfl_xor(s, off, 16);
    if (gg == 0) out[row0 + rr] = s + b5[0] + s_part[rr];
  }
}

extern "C" void kernel_launch(void* const* d_in, const int* in_sizes, int n_in,
                              void* d_out, int out_size, void* d_ws, size_t ws_size,
                              hipStream_t stream) {
  const float* x_int = (const float*)d_in[0];
  const int*   x_cat = (const int*)d_in[1];
  const float* emb   = (const float*)d_in[2];
  const float* lin   = (const float*)d_in[3];
  const float* W_num = (const float*)d_in[4];
  const float* b_num = (const float*)d_in[5];
  const float* bias  = (const float*)d_in[6];
  const float* W1 = (const float*)d_in[7];  const float* b1 = (const float*)d_in[8];
  const float* W2 = (const float*)d_in[9];  const float* b2 = (const float*)d_in[10];
  const float* W3 = (const float*)d_in[11]; const float* b3 = (const float*)d_in[12];
  const float* W4 = (const float*)d_in[13]; const float* b4 = (const float*)d_in[14];
  const float* W5 = (const float*)d_in[15]; const float* b5 = (const float*)d_in[16];
  float* out = (float*)d_out;

  k_fused<<<NROWS / 64, 1024, 0, stream>>>(x_int, x_cat, emb, lin, W_num, b_num, bias,
                                           W1, b1, W2, b2, W3, b3, W4, b4, W5, b5,
                                           out);
}

// Round 11
// 63.491 us; speedup vs baseline: 1.1514x; 1.1514x over previous
//
#include <hip/hip_runtime.h>
#include <hip/hip_bf16.h>
#include <stdint.h>

typedef __bf16 bf16x8 __attribute__((ext_vector_type(8)));
typedef __bf16 bf16x4 __attribute__((ext_vector_type(4)));
typedef float  f32x4  __attribute__((ext_vector_type(4)));

#define NROWS 16384
#define NFEAT 26
#define VOCAB 100000

// lgkm-only barrier: syncs LDS but leaves global (vmcnt) prefetches in flight.
__device__ __forceinline__ void bar_lgkm() {
  asm volatile("s_waitcnt lgkmcnt(0)" ::: "memory");
  __builtin_amdgcn_s_barrier();
  asm volatile("" ::: "memory");
}

// ---------------- per-layer GEMM (layers 2-4): A (LDS) x W[KREAL][N] fp32 ----------
template<int KPAD, int KREAL, int N, int NCT, int WS>
__device__ __forceinline__ void mlp_layer(const float* __restrict__ W,
                                          const float* __restrict__ bias,
                                          const __bf16* Ain, __bf16* Aout,
                                          int w, int lane) {
  constexpr int LDA = KPAD + 8, LDO = N + 8;
  const int lrow = lane & 15;
  const int kg = (lane >> 4) * 8;

  f32x4 acc[NCT][4];
  #pragma unroll
  for (int j = 0; j < NCT; ++j)
    #pragma unroll
    for (int m = 0; m < 4; ++m)
      #pragma unroll
      for (int i = 0; i < 4; ++i) acc[j][m][i] = 0.f;

  int col[NCT];
  #pragma unroll
  for (int j = 0; j < NCT; ++j) col[j] = (w + j * WS) * 16 + lrow;

  for (int k0 = 0; k0 < KREAL; k0 += 32) {
    bf16x8 af[4];
    #pragma unroll
    for (int m = 0; m < 4; ++m)
      af[m] = *(const bf16x8*)(Ain + (m * 16 + lrow) * LDA + k0 + kg);
    #pragma unroll
    for (int j = 0; j < NCT; ++j) {
      bf16x8 bw;
      #pragma unroll
      for (int i = 0; i < 8; ++i)
        bw[i] = (__bf16)W[(size_t)(k0 + kg + i) * N + col[j]];
      #pragma unroll
      for (int m = 0; m < 4; ++m)
        acc[j][m] = __builtin_amdgcn_mfma_f32_16x16x32_bf16(af[m], bw, acc[j][m], 0, 0, 0);
    }
  }

  const int rbase = (lane >> 4) * 4;
  #pragma unroll
  for (int j = 0; j < NCT; ++j) {
    float bv = bias[col[j]];
    #pragma unroll
    for (int m = 0; m < 4; ++m)
      #pragma unroll
      for (int i = 0; i < 4; ++i) {
        float v = acc[j][m][i] + bv;
        v = fmaxf(v, 0.f);
        Aout[(m * 16 + rbase + i) * LDO + col[j]] = (__bf16)v;
      }
  }
}

// ---------------- fused: deep-pipelined {gather || layer-1} + layers 2-5 ----------
// 64 rows/block, 1024 threads (16 waves). Layer-1 runs a flat 14 K-step loop:
// W1 fragments register-prefetched 2 K-steps ahead (L2 stream, issued FIRST each
// step so it is always OLDER than in-flight emb gathers in the in-order vmcnt
// queue); emb gather prefetched 3 chunks ahead (covers ~900cy HBM latency).
__global__ __launch_bounds__(1024) void k_fused(
    const float* __restrict__ x_int,   // [B,13]
    const int*   __restrict__ x_cat,   // [B,26]
    const float* __restrict__ emb,     // [26,V,16]
    const float* __restrict__ lin,     // [26,V]
    const float* __restrict__ W_num,   // [13]
    const float* __restrict__ b_num,   // [1]
    const float* __restrict__ bias0,   // [1]
    const float* __restrict__ W1, const float* __restrict__ b1,
    const float* __restrict__ W2, const float* __restrict__ b2,
    const float* __restrict__ W3, const float* __restrict__ b3,
    const float* __restrict__ W4, const float* __restrict__ b4,
    const float* __restrict__ W5, const float* __restrict__ b5,
    float* __restrict__ out) {
  // LDS (125184 B): A0 @0 : 64x456 bf16; A1 @58368 : 64x520 bf16 (s_idx aliases
  // A1 head, dead before first A1 write); s_part @124928 : 64 f32.
  __shared__ __align__(16) char smem[125184];
  __bf16* A0 = (__bf16*)smem;
  __bf16* A1 = (__bf16*)(smem + 58368);
  int* s_idx = (int*)(smem + 58368);
  float* s_part = (float*)(smem + 124928);

  const int t = threadIdx.x;
  const int row0 = blockIdx.x * 64;
  const int w = t >> 6, lane = t & 63;
  const int lrow = lane & 15, kg = (lane >> 4) * 8;

  // ---- stage categorical indices ----
  for (int i = t; i < 64 * NFEAT; i += 1024) {
    int r = i / NFEAT, f = i - r * NFEAT;
    s_idx[i] = x_cat[(size_t)(row0 + r) * NFEAT + f];
  }
  __syncthreads();

  const int r = t >> 4, d = t & 15;
  const int g = d >> 2, q = d & 3;   // feature-group (mod 4), dim-quad

  const int colL1[2] = { w * 16 + lrow, (w + 16) * 16 + lrow };

  // ---- W1 K-step register prefetch, depth 2 (FIRST into the vmcnt queue) ----
  float wbuf[2][2][8];
  #pragma unroll
  for (int sb = 0; sb < 2; ++sb)
    #pragma unroll
    for (int j = 0; j < 2; ++j)
      #pragma unroll
      for (int i = 0; i < 8; ++i)
        wbuf[sb][j][i] = W1[(size_t)(sb * 32 + kg + i) * 512 + colL1[j]];

  // ---- emb gather prefetch, depth 3 ----
  f32x4 pe[4];
  #pragma unroll
  for (int c = 0; c < 3; ++c) {
    int fc = 4 * c + g;
    int idx = s_idx[r * NFEAT + fc];
    pe[c] = *(const f32x4*)(emb + ((size_t)fc * VOCAB + idx) * 16 + q * 4);
  }

  // ---- linear terms + x_int tail (prologue tail of the vmcnt queue) ----
  float lin_s = 0.f;
  if (d < 13) {
    lin_s = lin[(size_t)d * VOCAB + s_idx[r * NFEAT + d]]
          + lin[(size_t)(d + 13) * VOCAB + s_idx[r * NFEAT + d + 13]]
          + x_int[(size_t)(row0 + r) * 13 + d] * W_num[d];
  }
  float xv[4] = {0.f, 0.f, 0.f, 0.f};
  if (d >= 8 && d < 12) {
    int base = (d - 8) * 4;
    #pragma unroll
    for (int i = 0; i < 4; ++i)
      if (base + i < 13) xv[i] = x_int[(size_t)(row0 + r) * 13 + base + i];
  }

  // ---- layer-1 accumulators (2 col-tiles x 4 m-tiles) ----
  f32x4 acc[2][4];
  #pragma unroll
  for (int j = 0; j < 2; ++j)
    #pragma unroll
    for (int m = 0; m < 4; ++m)
      #pragma unroll
      for (int i = 0; i < 4; ++i) acc[j][m][i] = 0.f;

  float fsum[4] = {0.f,0.f,0.f,0.f}, fsq[4] = {0.f,0.f,0.f,0.f};

  // ---- flat 14 K-step loop (7 chunks x 2 K-steps) ----
  #pragma unroll
  for (int s = 0; s < 14; ++s) {
    const int c = s >> 1;
    // 1. cvt W(s) out of its buffer (waits only its own, 2-ks-old loads)
    bf16x8 bw[2];
    #pragma unroll
    for (int j = 0; j < 2; ++j)
      #pragma unroll
      for (int i = 0; i < 8; ++i)
        bw[j][i] = (__bf16)wbuf[s & 1][j][i];
    // 2. reload freed buffer with W(s+2) — issued before any same-step emb load
    if (s + 2 < 14) {
      #pragma unroll
      for (int j = 0; j < 2; ++j)
        #pragma unroll
        for (int i = 0; i < 8; ++i) {
          const int k = (s + 2) * 32 + kg + i;
          float v = 0.f;
          if (s + 2 < 13 || k < 429)
            v = W1[(size_t)k * 512 + colL1[j]];
          wbuf[s & 1][j][i] = v;
        }
    }
    // 3. chunk boundary: emb issue (3 ahead) + consume + ds_write + barrier
    if ((s & 1) == 0) {
      if (c + 3 <= 6) {
        const int fc = 4 * (c + 3) + g;
        if (fc < NFEAT) {
          int idx = s_idx[r * NFEAT + fc];
          pe[(c + 3) & 3] = *(const f32x4*)(emb + ((size_t)fc * VOCAB + idx) * 16 + q * 4);
        }
      }
      const int colbase = c * 64 + g * 16 + q * 4;
      if (4 * c + g < NFEAT) {
        f32x4 cv = pe[c & 3];
        bf16x4 pk;
        #pragma unroll
        for (int i = 0; i < 4; ++i) {
          fsum[i] += cv[i]; fsq[i] += cv[i] * cv[i];
          pk[i] = (__bf16)cv[i];
        }
        *(bf16x4*)(A0 + r * 456 + colbase) = pk;
      } else {                     // c==6, g>=2: x_int + zero pad
        bf16x4 pk;
        #pragma unroll
        for (int i = 0; i < 4; ++i) pk[i] = (__bf16)xv[i];
        *(bf16x4*)(A0 + r * 456 + colbase) = pk;
      }
      bar_lgkm();                  // in-flight vmcnt prefetches survive
    }
    // 4. A-fragments from LDS + MFMA
    bf16x8 af[4];
    #pragma unroll
    for (int m = 0; m < 4; ++m)
      af[m] = *(const bf16x8*)(A0 + (m * 16 + lrow) * 456 + s * 32 + kg);
    #pragma unroll
    for (int j = 0; j < 2; ++j)
      #pragma unroll
      for (int m = 0; m < 4; ++m)
        acc[j][m] = __builtin_amdgcn_mfma_f32_16x16x32_bf16(af[m], bw[j], acc[j][m], 0, 0, 0);
  }

  // ---- layer-1 epilogue: bias + ReLU -> A1 (s_idx alias dead: safe now) ----
  {
    const int rbase = (lane >> 4) * 4;
    #pragma unroll
    for (int j = 0; j < 2; ++j) {
      float bv = b1[colL1[j]];
      #pragma unroll
      for (int m = 0; m < 4; ++m)
        #pragma unroll
        for (int i = 0; i < 4; ++i) {
          float v = acc[j][m][i] + bv;
          v = fmaxf(v, 0.f);
          A1[(m * 16 + rbase + i) * 520 + colL1[j]] = (__bf16)v;
        }
    }
  }

  // ---- FM + linear combine -> s_part ----
  {
    #pragma unroll
    for (int i = 0; i < 4; ++i) {
      fsum[i] += __shfl_xor(fsum[i], 4); fsq[i] += __shfl_xor(fsq[i], 4);
      fsum[i] += __shfl_xor(fsum[i], 8); fsq[i] += __shfl_xor(fsq[i], 8);
    }
    float fmq = 0.f;
    #pragma unroll
    for (int i = 0; i < 4; ++i) fmq += fsum[i] * fsum[i] - fsq[i];
    fmq += __shfl_xor(fmq, 1);
    fmq += __shfl_xor(fmq, 2);     // full FM, replicated over d
    float linred = lin_s;
    #pragma unroll
    for (int off = 1; off < 16; off <<= 1) linred += __shfl_xor(linred, off, 16);
    if (d == 0) s_part[r] = 0.5f * fmq + linred + bias0[0] + b_num[0];
  }
  __syncthreads();

  // ---- layers 2-4 (fp32 weights direct from read-only inputs) ----
  mlp_layer<512, 512, 256, 1, 16>(W2, b2, A1, A0, w, lane);
  __syncthreads();
  if (w < 8) mlp_layer<256, 256, 128, 1, 8>(W3, b3, A0, A1, w, lane);
  __syncthreads();
  if (w < 4) mlp_layer<128, 128, 64, 1, 4>(W4, b4, A1, A0, w, lane);
  __syncthreads();

  // ---- final 64->1 dot + combine ----
  {
    const int rr = t >> 4, gg = t & 15;
    float s = 0.f;
    #pragma unroll
    for (int i = 0; i < 4; ++i)
      s += (float)A0[rr * 72 + gg * 4 + i] * W5[gg * 4 + i];
    #pragma unroll
    for (int off = 1; off < 16; off <<= 1) s += __shfl_xor(s, off, 16);
    if (gg == 0) out[row0 + rr] = s + b5[0] + s_part[rr];
  }
}

extern "C" void kernel_launch(void* const* d_in, const int* in_sizes, int n_in,
                              void* d_out, int out_size, void* d_ws, size_t ws_size,
                              hipStream_t stream) {
  const float* x_int = (const float*)d_in[0];
  const int*   x_cat = (const int*)d_in[1];
  const float* emb   = (const float*)d_in[2];
  const float* lin   = (const float*)d_in[3];
  const float* W_num = (const float*)d_in[4];
  const float* b_num = (const float*)d_in[5];
  const float* bias  = (const float*)d_in[6];
  const float* W1 = (const float*)d_in[7];  const float* b1 = (const float*)d_in[8];
  const float* W2 = (const float*)d_in[9];  const float* b2 = (const float*)d_in[10];
  const float* W3 = (const float*)d_in[11]; const float* b3 = (const float*)d_in[12];
  const float* W4 = (const float*)d_in[13]; const float* b4 = (const float*)d_in[14];
  const float* W5 = (const float*)d_in[15]; const float* b5 = (const float*)d_in[16];
  float* out = (float*)d_out;

  k_fused<<<NROWS / 64, 1024, 0, stream>>>(x_int, x_cat, emb, lin, W_num, b_num, bias,
                                           W1, b1, W2, b2, W3, b3, W4, b4, W5, b5,
                                           out);
}

// Round 12
// 54.962 us; speedup vs baseline: 1.3300x; 1.1552x over previous
//
#include <hip/hip_runtime.h>
#include <hip/hip_bf16.h>
#include <stdint.h>

typedef __bf16 bf16x8 __attribute__((ext_vector_type(8)));
typedef __bf16 bf16x4 __attribute__((ext_vector_type(4)));
typedef float  f32x4  __attribute__((ext_vector_type(4)));

#define NROWS 16384
#define NFEAT 26
#define VOCAB 100000

// lgkm-only barrier: syncs LDS but leaves global (vmcnt) prefetches in flight.
__device__ __forceinline__ void bar_lgkm() {
  asm volatile("s_waitcnt lgkmcnt(0)" ::: "memory");
  __builtin_amdgcn_s_barrier();
  asm volatile("" ::: "memory");
}

// ---------------- per-layer GEMM (layers 2-4): A (LDS) x W[KREAL][N] fp32 ----------
template<int KPAD, int KREAL, int N, int NCT, int WS>
__device__ __forceinline__ void mlp_layer(const float* __restrict__ W,
                                          const float* __restrict__ bias,
                                          const __bf16* Ain, __bf16* Aout,
                                          int w, int lane) {
  constexpr int LDA = KPAD + 8, LDO = N + 8;
  const int lrow = lane & 15;
  const int kg = (lane >> 4) * 8;

  f32x4 acc[NCT][4];
  #pragma unroll
  for (int j = 0; j < NCT; ++j)
    #pragma unroll
    for (int m = 0; m < 4; ++m)
      #pragma unroll
      for (int i = 0; i < 4; ++i) acc[j][m][i] = 0.f;

  int col[NCT];
  #pragma unroll
  for (int j = 0; j < NCT; ++j) col[j] = (w + j * WS) * 16 + lrow;

  for (int k0 = 0; k0 < KREAL; k0 += 32) {
    bf16x8 af[4];
    #pragma unroll
    for (int m = 0; m < 4; ++m)
      af[m] = *(const bf16x8*)(Ain + (m * 16 + lrow) * LDA + k0 + kg);
    #pragma unroll
    for (int j = 0; j < NCT; ++j) {
      bf16x8 bw;
      #pragma unroll
      for (int i = 0; i < 8; ++i)
        bw[i] = (__bf16)W[(size_t)(k0 + kg + i) * N + col[j]];
      #pragma unroll
      for (int m = 0; m < 4; ++m)
        acc[j][m] = __builtin_amdgcn_mfma_f32_16x16x32_bf16(af[m], bw, acc[j][m], 0, 0, 0);
    }
  }

  const int rbase = (lane >> 4) * 4;
  #pragma unroll
  for (int j = 0; j < NCT; ++j) {
    float bv = bias[col[j]];
    #pragma unroll
    for (int m = 0; m < 4; ++m)
      #pragma unroll
      for (int i = 0; i < 4; ++i) {
        float v = acc[j][m][i] + bv;
        v = fmaxf(v, 0.f);
        Aout[(m * 16 + rbase + i) * LDO + col[j]] = (__bf16)v;
      }
  }
}

// ---------------- fused: deep-pipelined {gather || layer-1} + layers 2-5 ----------
// 64 rows/block, 1024 threads (16 waves), __launch_bounds__(1024,4) -> 128 VGPR cap
// (R11 profile showed the default heuristic caps at 64 VGPR and spills 53 MB of
// pipeline state to scratch). W1 fragments register-prefetched 1 K-step ahead
// (issued FIRST each step -> always OLDER than emb gathers in the in-order vmcnt
// queue, so consuming W never drains the young emb prefetches); emb gather
// prefetched 3 chunks ahead.
__global__ __launch_bounds__(1024, 4) void k_fused(
    const float* __restrict__ x_int,   // [B,13]
    const int*   __restrict__ x_cat,   // [B,26]
    const float* __restrict__ emb,     // [26,V,16]
    const float* __restrict__ lin,     // [26,V]
    const float* __restrict__ W_num,   // [13]
    const float* __restrict__ b_num,   // [1]
    const float* __restrict__ bias0,   // [1]
    const float* __restrict__ W1, const float* __restrict__ b1,
    const float* __restrict__ W2, const float* __restrict__ b2,
    const float* __restrict__ W3, const float* __restrict__ b3,
    const float* __restrict__ W4, const float* __restrict__ b4,
    const float* __restrict__ W5, const float* __restrict__ b5,
    float* __restrict__ out) {
  // LDS (125184 B): A0 @0 : 64x456 bf16; A1 @58368 : 64x520 bf16 (s_idx aliases
  // A1 head, dead before first A1 write); s_part @124928 : 64 f32.
  __shared__ __align__(16) char smem[125184];
  __bf16* A0 = (__bf16*)smem;
  __bf16* A1 = (__bf16*)(smem + 58368);
  int* s_idx = (int*)(smem + 58368);
  float* s_part = (float*)(smem + 124928);

  const int t = threadIdx.x;
  const int row0 = blockIdx.x * 64;
  const int w = t >> 6, lane = t & 63;
  const int lrow = lane & 15, kg = (lane >> 4) * 8;

  // ---- stage categorical indices ----
  for (int i = t; i < 64 * NFEAT; i += 1024) {
    int r = i / NFEAT, f = i - r * NFEAT;
    s_idx[i] = x_cat[(size_t)(row0 + r) * NFEAT + f];
  }
  __syncthreads();

  const int r = t >> 4, d = t & 15;
  const int g = d >> 2, q = d & 3;   // feature-group (mod 4), dim-quad

  const int colL1[2] = { w * 16 + lrow, (w + 16) * 16 + lrow };

  // ---- W1 K-step register prefetch, depth 1 (FIRST into the vmcnt queue) ----
  float wbuf[2][8];
  #pragma unroll
  for (int j = 0; j < 2; ++j)
    #pragma unroll
    for (int i = 0; i < 8; ++i)
      wbuf[j][i] = W1[(size_t)(kg + i) * 512 + colL1[j]];

  // ---- emb gather prefetch, depth 3 ----
  f32x4 pe[4];
  #pragma unroll
  for (int c = 0; c < 3; ++c) {
    int fc = 4 * c + g;
    int idx = s_idx[r * NFEAT + fc];
    pe[c] = *(const f32x4*)(emb + ((size_t)fc * VOCAB + idx) * 16 + q * 4);
  }

  // ---- linear terms + x_int tail (prologue tail of the vmcnt queue) ----
  float lin_s = 0.f;
  if (d < 13) {
    lin_s = lin[(size_t)d * VOCAB + s_idx[r * NFEAT + d]]
          + lin[(size_t)(d + 13) * VOCAB + s_idx[r * NFEAT + d + 13]]
          + x_int[(size_t)(row0 + r) * 13 + d] * W_num[d];
  }
  float xv[4] = {0.f, 0.f, 0.f, 0.f};
  if (d >= 8 && d < 12) {
    int base = (d - 8) * 4;
    #pragma unroll
    for (int i = 0; i < 4; ++i)
      if (base + i < 13) xv[i] = x_int[(size_t)(row0 + r) * 13 + base + i];
  }

  // ---- layer-1 accumulators (2 col-tiles x 4 m-tiles) ----
  f32x4 acc[2][4];
  #pragma unroll
  for (int j = 0; j < 2; ++j)
    #pragma unroll
    for (int m = 0; m < 4; ++m)
      #pragma unroll
      for (int i = 0; i < 4; ++i) acc[j][m][i] = 0.f;

  float fsum[4] = {0.f,0.f,0.f,0.f}, fsq[4] = {0.f,0.f,0.f,0.f};

  // ---- flat 14 K-step loop (7 chunks x 2 K-steps) ----
  #pragma unroll
  for (int s = 0; s < 14; ++s) {
    const int c = s >> 1;
    // 1. cvt W(s) out of its buffer (drains only loads <= its own)
    bf16x8 bw[2];
    #pragma unroll
    for (int j = 0; j < 2; ++j)
      #pragma unroll
      for (int i = 0; i < 8; ++i)
        bw[j][i] = (__bf16)wbuf[j][i];
    // 2. reload buffer with W(s+1) — issued before any same-step emb load
    if (s + 1 < 14) {
      #pragma unroll
      for (int j = 0; j < 2; ++j)
        #pragma unroll
        for (int i = 0; i < 8; ++i) {
          const int k = (s + 1) * 32 + kg + i;
          float v = 0.f;
          if (s + 1 < 13 || k < 429)
            v = W1[(size_t)k * 512 + colL1[j]];
          wbuf[j][i] = v;
        }
    }
    // 3. chunk boundary: emb issue (3 ahead) + consume + ds_write + barrier
    if ((s & 1) == 0) {
      if (c + 3 <= 6) {
        const int fc = 4 * (c + 3) + g;
        if (fc < NFEAT) {
          int idx = s_idx[r * NFEAT + fc];
          pe[(c + 3) & 3] = *(const f32x4*)(emb + ((size_t)fc * VOCAB + idx) * 16 + q * 4);
        }
      }
      const int colbase = c * 64 + g * 16 + q * 4;
      if (4 * c + g < NFEAT) {
        f32x4 cv = pe[c & 3];
        bf16x4 pk;
        #pragma unroll
        for (int i = 0; i < 4; ++i) {
          fsum[i] += cv[i]; fsq[i] += cv[i] * cv[i];
          pk[i] = (__bf16)cv[i];
        }
        *(bf16x4*)(A0 + r * 456 + colbase) = pk;
      } else {                     // c==6, g>=2: x_int + zero pad
        bf16x4 pk;
        #pragma unroll
        for (int i = 0; i < 4; ++i) pk[i] = (__bf16)xv[i];
        *(bf16x4*)(A0 + r * 456 + colbase) = pk;
      }
      bar_lgkm();                  // in-flight vmcnt prefetches survive
    }
    // 4. A-fragments from LDS + MFMA
    bf16x8 af[4];
    #pragma unroll
    for (int m = 0; m < 4; ++m)
      af[m] = *(const bf16x8*)(A0 + (m * 16 + lrow) * 456 + s * 32 + kg);
    #pragma unroll
    for (int j = 0; j < 2; ++j)
      #pragma unroll
      for (int m = 0; m < 4; ++m)
        acc[j][m] = __builtin_amdgcn_mfma_f32_16x16x32_bf16(af[m], bw[j], acc[j][m], 0, 0, 0);
  }

  // ---- layer-1 epilogue: bias + ReLU -> A1 (s_idx alias dead: safe now) ----
  {
    const int rbase = (lane >> 4) * 4;
    #pragma unroll
    for (int j = 0; j < 2; ++j) {
      float bv = b1[colL1[j]];
      #pragma unroll
      for (int m = 0; m < 4; ++m)
        #pragma unroll
        for (int i = 0; i < 4; ++i) {
          float v = acc[j][m][i] + bv;
          v = fmaxf(v, 0.f);
          A1[(m * 16 + rbase + i) * 520 + colL1[j]] = (__bf16)v;
        }
    }
  }

  // ---- FM + linear combine -> s_part ----
  {
    #pragma unroll
    for (int i = 0; i < 4; ++i) {
      fsum[i] += __shfl_xor(fsum[i], 4); fsq[i] += __shfl_xor(fsq[i], 4);
      fsum[i] += __shfl_xor(fsum[i], 8); fsq[i] += __shfl_xor(fsq[i], 8);
    }
    float fmq = 0.f;
    #pragma unroll
    for (int i = 0; i < 4; ++i) fmq += fsum[i] * fsum[i] - fsq[i];
    fmq += __shfl_xor(fmq, 1);
    fmq += __shfl_xor(fmq, 2);     // full FM, replicated over d
    float linred = lin_s;
    #pragma unroll
    for (int off = 1; off < 16; off <<= 1) linred += __shfl_xor(linred, off, 16);
    if (d == 0) s_part[r] = 0.5f * fmq + linred + bias0[0] + b_num[0];
  }
  __syncthreads();

  // ---- layers 2-4 (fp32 weights direct from read-only inputs) ----
  mlp_layer<512, 512, 256, 1, 16>(W2, b2, A1, A0, w, lane);
  __syncthreads();
  if (w < 8) mlp_layer<256, 256, 128, 1, 8>(W3, b3, A0, A1, w, lane);
  __syncthreads();
  if (w < 4) mlp_layer<128, 128, 64, 1, 4>(W4, b4, A1, A0, w, lane);
  __syncthreads();

  // ---- final 64->1 dot + combine ----
  {
    const int rr = t >> 4, gg = t & 15;
    float s = 0.f;
    #pragma unroll
    for (int i = 0; i < 4; ++i)
      s += (float)A0[rr * 72 + gg * 4 + i] * W5[gg * 4 + i];
    #pragma unroll
    for (int off = 1; off < 16; off <<= 1) s += __shfl_xor(s, off, 16);
    if (gg == 0) out[row0 + rr] = s + b5[0] + s_part[rr];
  }
}

extern "C" void kernel_launch(void* const* d_in, const int* in_sizes, int n_in,
                              void* d_out, int out_size, void* d_ws, size_t ws_size,
                              hipStream_t stream) {
  const float* x_int = (const float*)d_in[0];
  const int*   x_cat = (const int*)d_in[1];
  const float* emb   = (const float*)d_in[2];
  const float* lin   = (const float*)d_in[3];
  const float* W_num = (const float*)d_in[4];
  const float* b_num = (const float*)d_in[5];
  const float* bias  = (const float*)d_in[6];
  const float* W1 = (const float*)d_in[7];  const float* b1 = (const float*)d_in[8];
  const float* W2 = (const float*)d_in[9];  const float* b2 = (const float*)d_in[10];
  const float* W3 = (const float*)d_in[11]; const float* b3 = (const float*)d_in[12];
  const float* W4 = (const float*)d_in[13]; const float* b4 = (const float*)d_in[14];
  const float* W5 = (const float*)d_in[15]; const float* b5 = (const float*)d_in[16];
  float* out = (float*)d_out;

  k_fused<<<NROWS / 64, 1024, 0, stream>>>(x_int, x_cat, emb, lin, W_num, b_num, bias,
                                           W1, b1, W2, b2, W3, b3, W4, b4, W5, b5,
                                           out);
}

// Round 13
// 53.642 us; speedup vs baseline: 1.3628x; 1.0246x over previous
//
#include <hip/hip_runtime.h>
#include <hip/hip_bf16.h>
#include <stdint.h>

typedef __bf16 bf16x8 __attribute__((ext_vector_type(8)));
typedef __bf16 bf16x4 __attribute__((ext_vector_type(4)));
typedef float  f32x4  __attribute__((ext_vector_type(4)));

#define NROWS 16384
#define NFEAT 26
#define VOCAB 100000

// ================= Kernel 1: pure gather + FM + linear =================
// 512 blocks x 512 thr; 32 rows/block, 16 thr/row (one f32x4 quad each).
// Single vmcnt stream per wave: all emb lines issued before any consume,
// consumed in issue order. No MFMA, no inner barriers.
__global__ __launch_bounds__(512, 8) void k_gather(
    const float* __restrict__ x_int, const int* __restrict__ x_cat,
    const float* __restrict__ emb, const float* __restrict__ lin,
    const float* __restrict__ W_num, const float* __restrict__ b_num,
    const float* __restrict__ bias0,
    __bf16* __restrict__ deep_in, float* __restrict__ partial) {
  __shared__ int s_idx[32 * NFEAT];
  const int t = threadIdx.x;
  const int row0 = blockIdx.x * 32;
  for (int i = t; i < 32 * NFEAT; i += 512) {
    int r = i / NFEAT, f = i - r * NFEAT;
    s_idx[i] = x_cat[(size_t)(row0 + r) * NFEAT + f];
  }
  __syncthreads();

  const int r = t >> 4, sub = t & 15, h = sub >> 2, q = sub & 3;
  const int row = row0 + r;
  const int sbase = r * NFEAT;

  // ---- issue ALL emb lines for this thread (f = 4j + h) ----
  f32x4 pf[7];
  #pragma unroll
  for (int j = 0; j < 7; ++j) {
    int f = 4 * j + h;
    if (f < NFEAT) {
      int idx = s_idx[sbase + f];
      pf[j] = *(const f32x4*)(emb + ((size_t)f * VOCAB + idx) * 16 + q * 4);
    }
  }

  // ---- linear terms (same stream, issued after; consumed last) ----
  float lt = lin[(size_t)sub * VOCAB + s_idx[sbase + sub]];
  if (sub < 10) lt += lin[(size_t)(sub + 16) * VOCAB + s_idx[sbase + sub + 16]];
  if (sub < 13) lt += x_int[(size_t)row * 13 + sub] * W_num[sub];

  // ---- x_int tail cols 416..447 (8 chunks of 4) ----
  if (sub < 8) {
    bf16x4 pk;
    #pragma unroll
    for (int i = 0; i < 4; ++i) {
      int c = sub * 4 + i;
      float v = (c < 13) ? x_int[(size_t)row * 13 + c] : 0.f;
      pk[i] = (__bf16)v;
    }
    *(bf16x4*)(deep_in + (size_t)row * 448 + 416 + sub * 4) = pk;
  }

  // ---- consume emb in issue order: FM partials + bf16 store ----
  float fsum[4] = {0.f,0.f,0.f,0.f}, fsq[4] = {0.f,0.f,0.f,0.f};
  #pragma unroll
  for (int j = 0; j < 7; ++j) {
    int f = 4 * j + h;
    if (f < NFEAT) {
      bf16x4 pk;
      #pragma unroll
      for (int i = 0; i < 4; ++i) {
        float v = pf[j][i];
        fsum[i] += v; fsq[i] += v * v;
        pk[i] = (__bf16)v;
      }
      *(bf16x4*)(deep_in + (size_t)row * 448 + f * 16 + q * 4) = pk;
    }
  }

  // ---- reduce: h (xor4,xor8) -> per-dim sums; dims; quad (xor1,xor2) ----
  #pragma unroll
  for (int i = 0; i < 4; ++i) {
    fsum[i] += __shfl_xor(fsum[i], 4); fsq[i] += __shfl_xor(fsq[i], 4);
    fsum[i] += __shfl_xor(fsum[i], 8); fsq[i] += __shfl_xor(fsq[i], 8);
  }
  float fmq = 0.f;
  #pragma unroll
  for (int i = 0; i < 4; ++i) fmq += fsum[i] * fsum[i] - fsq[i];
  fmq += __shfl_xor(fmq, 1);
  fmq += __shfl_xor(fmq, 2);
  lt += __shfl_xor(lt, 1); lt += __shfl_xor(lt, 2);
  lt += __shfl_xor(lt, 4); lt += __shfl_xor(lt, 8);
  if (sub == 0)
    partial[row] = 0.5f * fmq + lt + bias0[0] + b_num[0];
}

// ---------------- per-layer GEMM (layers 2-4): A (LDS) x W[KREAL][N] fp32 ----------
template<int KPAD, int KREAL, int N, int NCT, int WS>
__device__ __forceinline__ void mlp_layer(const float* __restrict__ W,
                                          const float* __restrict__ bias,
                                          const __bf16* Ain, __bf16* Aout,
                                          int w, int lane) {
  constexpr int LDA = KPAD + 8, LDO = N + 8;
  const int lrow = lane & 15;
  const int kg = (lane >> 4) * 8;

  f32x4 acc[NCT][4];
  #pragma unroll
  for (int j = 0; j < NCT; ++j)
    #pragma unroll
    for (int m = 0; m < 4; ++m)
      #pragma unroll
      for (int i = 0; i < 4; ++i) acc[j][m][i] = 0.f;

  int col[NCT];
  #pragma unroll
  for (int j = 0; j < NCT; ++j) col[j] = (w + j * WS) * 16 + lrow;

  for (int k0 = 0; k0 < KREAL; k0 += 32) {
    bf16x8 af[4];
    #pragma unroll
    for (int m = 0; m < 4; ++m)
      af[m] = *(const bf16x8*)(Ain + (m * 16 + lrow) * LDA + k0 + kg);
    #pragma unroll
    for (int j = 0; j < NCT; ++j) {
      bf16x8 bw;
      #pragma unroll
      for (int i = 0; i < 8; ++i)
        bw[i] = (__bf16)W[(size_t)(k0 + kg + i) * N + col[j]];
      #pragma unroll
      for (int m = 0; m < 4; ++m)
        acc[j][m] = __builtin_amdgcn_mfma_f32_16x16x32_bf16(af[m], bw, acc[j][m], 0, 0, 0);
    }
  }

  const int rbase = (lane >> 4) * 4;
  #pragma unroll
  for (int j = 0; j < NCT; ++j) {
    float bv = bias[col[j]];
    #pragma unroll
    for (int m = 0; m < 4; ++m)
      #pragma unroll
      for (int i = 0; i < 4; ++i) {
        float v = acc[j][m][i] + bv;
        v = fmaxf(v, 0.f);
        Aout[(m * 16 + rbase + i) * LDO + col[j]] = (__bf16)v;
      }
  }
}

// ================= Kernel 2: MLP (clean single W stream) =================
// 256 blocks x 1024 thr (16 waves), 1 block/CU (LDS-bound); 128 VGPR cap free.
__global__ __launch_bounds__(1024, 4) void k_mlp(
    const __bf16* __restrict__ deep_in, const float* __restrict__ partial,
    const float* __restrict__ W1, const float* __restrict__ b1,
    const float* __restrict__ W2, const float* __restrict__ b2,
    const float* __restrict__ W3, const float* __restrict__ b3,
    const float* __restrict__ W4, const float* __restrict__ b4,
    const float* __restrict__ W5, const float* __restrict__ b5,
    float* __restrict__ out) {
  // LDS (124928 B): A0 @0 : 64x456 bf16 (58368); A1 @58368 : 64x520 bf16 (66560).
  __shared__ __align__(16) char smem[124928];
  __bf16* A0 = (__bf16*)smem;
  __bf16* A1 = (__bf16*)(smem + 58368);

  const int t = threadIdx.x;
  const int row0 = blockIdx.x * 64;
  const int w = t >> 6, lane = t & 63;
  const int lrow = lane & 15, kg = (lane >> 4) * 8;

  // ---- stage deep_in tile -> A0 (coalesced 16B chunks; tile is contiguous) ----
  {
    const __bf16* src = deep_in + (size_t)row0 * 448;
    for (int i = t; i < 3584; i += 1024) {
      int rr = i / 56, cc = i - rr * 56;
      *(f32x4*)(A0 + rr * 456 + cc * 8) = *(const f32x4*)(src + (size_t)i * 8);
    }
  }
  __syncthreads();

  // ---- layer 1: barrier-free 14 K-step loop, W1 fp32 single stream ----
  f32x4 acc[2][4];
  #pragma unroll
  for (int j = 0; j < 2; ++j)
    #pragma unroll
    for (int m = 0; m < 4; ++m)
      #pragma unroll
      for (int i = 0; i < 4; ++i) acc[j][m][i] = 0.f;
  const int colL1[2] = { w * 16 + lrow, (w + 16) * 16 + lrow };

  #pragma unroll
  for (int s = 0; s < 14; ++s) {
    bf16x8 af[4];
    #pragma unroll
    for (int m = 0; m < 4; ++m)
      af[m] = *(const bf16x8*)(A0 + (m * 16 + lrow) * 456 + s * 32 + kg);
    #pragma unroll
    for (int j = 0; j < 2; ++j) {
      bf16x8 bw;
      #pragma unroll
      for (int i = 0; i < 8; ++i) {
        const int k = s * 32 + kg + i;
        float v;
        if (s < 13) v = W1[(size_t)k * 512 + colL1[j]];
        else        v = (k < 429) ? W1[(size_t)k * 512 + colL1[j]] : 0.f;
        bw[i] = (__bf16)v;
      }
      #pragma unroll
      for (int m = 0; m < 4; ++m)
        acc[j][m] = __builtin_amdgcn_mfma_f32_16x16x32_bf16(af[m], bw, acc[j][m], 0, 0, 0);
    }
  }

  // ---- layer-1 epilogue: bias + ReLU -> A1 ----
  {
    const int rbase = (lane >> 4) * 4;
    #pragma unroll
    for (int j = 0; j < 2; ++j) {
      float bv = b1[colL1[j]];
      #pragma unroll
      for (int m = 0; m < 4; ++m)
        #pragma unroll
        for (int i = 0; i < 4; ++i) {
          float v = acc[j][m][i] + bv;
          v = fmaxf(v, 0.f);
          A1[(m * 16 + rbase + i) * 520 + colL1[j]] = (__bf16)v;
        }
    }
  }
  __syncthreads();

  // ---- layers 2-4 (fp32 weights direct) ----
  mlp_layer<512, 512, 256, 1, 16>(W2, b2, A1, A0, w, lane);
  __syncthreads();
  if (w < 8) mlp_layer<256, 256, 128, 1, 8>(W3, b3, A0, A1, w, lane);
  __syncthreads();
  if (w < 4) mlp_layer<128, 128, 64, 1, 4>(W4, b4, A1, A0, w, lane);
  __syncthreads();

  // ---- final 64->1 dot + combine ----
  {
    const int rr = t >> 4, gg = t & 15;
    float s = 0.f;
    #pragma unroll
    for (int i = 0; i < 4; ++i)
      s += (float)A0[rr * 72 + gg * 4 + i] * W5[gg * 4 + i];
    #pragma unroll
    for (int off = 1; off < 16; off <<= 1) s += __shfl_xor(s, off, 16);
    if (gg == 0) out[row0 + rr] = s + b5[0] + partial[row0 + rr];
  }
}

extern "C" void kernel_launch(void* const* d_in, const int* in_sizes, int n_in,
                              void* d_out, int out_size, void* d_ws, size_t ws_size,
                              hipStream_t stream) {
  const float* x_int = (const float*)d_in[0];
  const int*   x_cat = (const int*)d_in[1];
  const float* emb   = (const float*)d_in[2];
  const float* lin   = (const float*)d_in[3];
  const float* W_num = (const float*)d_in[4];
  const float* b_num = (const float*)d_in[5];
  const float* bias  = (const float*)d_in[6];
  const float* W1 = (const float*)d_in[7];  const float* b1 = (const float*)d_in[8];
  const float* W2 = (const float*)d_in[9];  const float* b2 = (const float*)d_in[10];
  const float* W3 = (const float*)d_in[11]; const float* b3 = (const float*)d_in[12];
  const float* W4 = (const float*)d_in[13]; const float* b4 = (const float*)d_in[14];
  const float* W5 = (const float*)d_in[15]; const float* b5 = (const float*)d_in[16];
  float* out = (float*)d_out;

  char* ws = (char*)d_ws;
  __bf16* deep_in = (__bf16*)ws;                    // [16384][448] bf16 = 14,680,064 B
  float* partial = (float*)(ws + 14680064);         // [16384] f32

  k_gather<<<NROWS / 32, 512, 0, stream>>>(x_int, x_cat, emb, lin, W_num, b_num, bias,
                                           deep_in, partial);
  k_mlp<<<NROWS / 64, 1024, 0, stream>>>(deep_in, partial,
                                         W1, b1, W2, b2, W3, b3, W4, b4, W5, b5,
                                         out);
}